// Round 1
// baseline (225.544 us; speedup 1.0000x reference)
//
#include <hip/hip_runtime.h>

// Conv1d as implicit GEMM on MFMA bf16 — R6.
// out[n,f,t] = sum_{c,k} x[n,c,t+k] * w[f,c,k] + b[f]
// N=32, C=64, W=4096, F=128, WW=64, out_W=4033. Output fp32.
//
// R6 vs R5: occupancy 2 -> 4 waves/SIMD.
//  * F split across blocks: each block does 64 f x 256 t. Grid 1024 = 4
//    blocks/CU (was 512 = 2). wls halves to 32 KB -> LDS ~35 KB/block.
//  * Per-wave tile 32f x 128t: acc[8][2] = 64 acc regs (was 128);
//    __launch_bounds__(256,4) to force combined VGPR+AGPR <= 128.
//  * A-fragments built per-ms-pair (Ae/Ao) instead of all 8 live -> lower
//    register pressure.
//  * f-half encoded in blockIdx.x bit 4: the two blocks sharing an
//    x-window are bx and bx+16 -> same XCD (%8) -> x L2 reuse.

#define C_TOT   64
#define F_TOT   128
#define F_BLK   64
#define KW      64
#define OUT_W   4033
#define W_IN    4096
#define N_BATCH 32
#define T_BLK   256
#define CH      2             // channels per pipeline stage
#define XWIN    320           // shorts needed per channel window (256 + 64)
#define XSTR    384           // xls channel stride (shorts)
#define TRS     260           // transpose LDS row stride (dwords)

typedef __attribute__((ext_vector_type(8))) short  short8;
typedef __attribute__((ext_vector_type(4))) float  floatx4;

union Frag { unsigned int u[4]; short8 v; };

__device__ inline unsigned short f32_to_bf16(float f) {
  unsigned int u = __float_as_uint(f);
  u += 0x7FFF + ((u >> 16) & 1);
  return (unsigned short)(u >> 16);
}

__device__ inline void async16(const unsigned short* g, unsigned short* l) {
  __builtin_amdgcn_global_load_lds(
      (const __attribute__((address_space(1))) unsigned int*)g,
      (__attribute__((address_space(3))) unsigned int*)l, 16, 0, 0);
}

// ---------------- prep: w fp32 -> bf16 swizzled [c][f][(k>>3)^(f&7)][k&7] ----
__global__ __launch_bounds__(256) void conv1d_prep(
    const float* __restrict__ w, unsigned short* __restrict__ wsw) {
  int i4 = blockIdx.x * 256 + threadIdx.x;   // float4 index into w
  if (i4 < F_TOT * C_TOT * KW / 4) {
    int k4 = (i4 & 15) * 4;
    int c  = (i4 >> 4) & 63;
    int f  = i4 >> 10;
    float4 v = *(const float4*)&w[(size_t)i4 * 4];
    ushort4 o;
    o.x = f32_to_bf16(v.x); o.y = f32_to_bf16(v.y);
    o.z = f32_to_bf16(v.z); o.w = f32_to_bf16(v.w);
    int chunk = (k4 >> 3) ^ (f & 7);
    *(ushort4*)&wsw[((size_t)(c * F_TOT + f) * 8 + chunk) * 8 + (k4 & 7)] = o;
  }
}

// ---------------- main GEMM ----------------
__global__ __launch_bounds__(256, 4) void conv1d_mfma(
    const float* __restrict__ x, const unsigned short* __restrict__ wsw,
    const float* __restrict__ b, float* __restrict__ out) {
  __shared__ union SM {
    struct {
      unsigned short wls[2][CH * F_BLK * KW];  // 2 x 16 KB
      unsigned short xls[2][CH * XSTR];        // 2 x 1.5 KB
    } k;
    float tr[32 * TRS];                        // 33.3 KB transpose buffer
  } sm;

  const int tid  = threadIdx.x;
  const int lane = tid & 63;
  const int wv   = tid >> 6;     // 0..3
  const int q    = lane >> 4;    // 0..3
  const int col  = lane & 15;
  const int n    = blockIdx.y;
  const int bx   = blockIdx.x;   // bit4 = f-half, bits0..3 = t-block
  const int t0   = (bx & 15) * T_BLK;
  const int FB   = (bx >> 4) * F_BLK;   // f base for this block
  const int fq   = wv & 1;       // f quarter within block (32 f)
  const int th   = wv >> 1;      // t half (128 t)

  // x staging role: 160 threads, one float4 each (2 ch x 80 float4)
  const int xc = tid / 80;              // channel-within-group
  const int xi = (tid - xc * 80) * 4;   // short offset 0..316
  const float* xrowb = x + (size_t)n * C_TOT * W_IN;

  floatx4 acc[8][2];             // [ms][ft]
#pragma unroll
  for (int ms = 0; ms < 8; ++ms)
#pragma unroll
    for (int ft = 0; ft < 2; ++ft) acc[ms][ft] = (floatx4)0.0f;

#define LOAD_X(cgx, vv)                                                         \
  {                                                                             \
    const float* src = xrowb + (size_t)((cgx) * CH + xc) * W_IN;                \
    int gt = t0 + xi;                                                           \
    if (gt + 3 < W_IN) vv = *(const float4*)(src + gt);                         \
    else {                                                                      \
      if (gt < W_IN)     vv.x = src[gt];                                        \
      if (gt + 1 < W_IN) vv.y = src[gt + 1];                                    \
      if (gt + 2 < W_IN) vv.z = src[gt + 2];                                    \
    }                                                                           \
  }

#define WRITE_X(p, vv)                                                          \
  {                                                                             \
    ushort4 o;                                                                  \
    o.x = f32_to_bf16(vv.x); o.y = f32_to_bf16(vv.y);                           \
    o.z = f32_to_bf16(vv.z); o.w = f32_to_bf16(vv.w);                           \
    *(ushort4*)&sm.k.xls[p][xc * XSTR + xi] = o;                                \
  }

  // w staging: per cg, CH*64f*64k shorts = 8192 shorts = 16 KB.
  // local off = (wv*4+s)*512 + lane*8; chl = off>>12; rem = off&4095.
  // global: (( (cg*CH+chl)*F_TOT + FB )*KW) + rem  (64 f rows contiguous).
#define STAGE_W(cg_, p_)                                                        \
  {                                                                             \
    const unsigned short* wb = wsw + ((size_t)(cg_) * CH * F_TOT + FB) * KW;    \
    _Pragma("unroll")                                                           \
    for (int s = 0; s < 4; ++s) {                                               \
      int off = (wv * 4 + s) * 512 + lane * 8;                                  \
      int chl = off >> 12;                                                      \
      int rem = off & 4095;                                                     \
      async16(wb + (size_t)chl * F_TOT * KW + rem, &sm.k.wls[p_][off]);         \
    }                                                                           \
  }

  // prologue: stage cg=0 into buffer 0
  if (tid < 160) {
    float4 xv = {0.f, 0.f, 0.f, 0.f};
    LOAD_X(0, xv)
    WRITE_X(0, xv)
  }
  STAGE_W(0, 0)
  __syncthreads();

  for (int cg = 0; cg < C_TOT / CH; ++cg) {
    const int p = cg & 1;
    const bool pre = (cg < C_TOT / CH - 1);
    float4 xv = {0.f, 0.f, 0.f, 0.f};
    if (pre && tid < 160) LOAD_X(cg + 1, xv)   // issue loads; land during compute
    if (pre) STAGE_W(cg + 1, p ^ 1)

#pragma unroll
    for (int chl = 0; chl < CH; ++chl) {
      const unsigned short* xpb = &sm.k.xls[p][chl * XSTR];
      const unsigned short* wpb = &sm.k.wls[p][chl * F_BLK * KW];
#pragma unroll
      for (int h = 0; h < 2; ++h) {
        // A window: 16 shorts at byte offset 16*col + 256*th + 64*h + 16*q
        const int ab = 16 * col + 256 * th + 64 * h + 16 * q;
        const uint4 d0 = *(const uint4*)((const char*)xpb + ab);
        const uint4 d1 = *(const uint4*)((const char*)xpb + ab + 16);
        const unsigned int D[8] = {d0.x, d0.y, d0.z, d0.w, d1.x, d1.y, d1.z, d1.w};
        const int bs = ((h * 4 + q) ^ (col & 7)) * 8;  // swizzled k-chunk (shorts)
        const short8 bf0 = *(const short8*)&wpb[(fq * 32 + col) * KW + bs];
        const short8 bf1 = *(const short8*)&wpb[(fq * 32 + 16 + col) * KW + bs];
#pragma unroll
        for (int s = 0; s < 4; ++s) {
          Frag Ae, Ao;
#pragma unroll
          for (int i = 0; i < 4; ++i) {
            Ae.u[i] = D[s + i];                                // even ms
            Ao.u[i] = (D[s + i] >> 16) | (D[s + i + 1] << 16); // odd ms
          }
          acc[2 * s][0] =
              __builtin_amdgcn_mfma_f32_16x16x32_bf16(Ae.v, bf0, acc[2 * s][0], 0, 0, 0);
          acc[2 * s][1] =
              __builtin_amdgcn_mfma_f32_16x16x32_bf16(Ae.v, bf1, acc[2 * s][1], 0, 0, 0);
          acc[2 * s + 1][0] =
              __builtin_amdgcn_mfma_f32_16x16x32_bf16(Ao.v, bf0, acc[2 * s + 1][0], 0, 0, 0);
          acc[2 * s + 1][1] =
              __builtin_amdgcn_mfma_f32_16x16x32_bf16(Ao.v, bf1, acc[2 * s + 1][1], 0, 0, 0);
        }
      }
    }
    if (pre && tid < 160) WRITE_X(p ^ 1, xv)
    __syncthreads();
  }

  // ---- epilogue: LDS transpose to [f][t], coalesced float4 stores ----
  // acc[ms][ft][r]: t_loc = 32q + 8r + ms + 128*th, f = FB + 32*fq + 16*ft + col
  const int fs_w  = fq * 16 + col;      // f-slot for writes (0..31)
  const int fs_r  = tid >> 3;           // f-slot for reads (0..31)
  const int seg   = tid & 7;
  const size_t ob = ((size_t)n * F_TOT) * OUT_W;

#pragma unroll
  for (int j = 0; j < 2; ++j) {         // round j handles ft == j (COMPILE-TIME)
#pragma unroll
    for (int r = 0; r < 4; ++r)
#pragma unroll
      for (int g = 0; g < 2; ++g) {
        float4 vv;
        vv.x = acc[g * 4 + 0][j][r];
        vv.y = acc[g * 4 + 1][j][r];
        vv.z = acc[g * 4 + 2][j][r];
        vv.w = acc[g * 4 + 3][j][r];
        int tl = 32 * q + 8 * r + 4 * g + 128 * th;
        *(float4*)&sm.tr[fs_w * TRS + tl] = vv;
      }
    __syncthreads();
    const int f = FB + (fs_r >> 4) * 32 + j * 16 + (fs_r & 15);
    const float bias = b[f];
    const size_t obf = ob + (size_t)f * OUT_W;
#pragma unroll
    for (int j2 = 0; j2 < 8; ++j2) {
      int tl = seg * 4 + 32 * j2;
      float4 vv = *(const float4*)&sm.tr[fs_r * TRS + tl];
      vv.x += bias; vv.y += bias; vv.z += bias; vv.w += bias;
      int t = t0 + tl;
      if (t + 3 < OUT_W) {
        *(float4*)&out[obf + t] = vv;
      } else {
        float e[4] = {vv.x, vv.y, vv.z, vv.w};
#pragma unroll
        for (int u = 0; u < 4; ++u)
          if (t + u < OUT_W) out[obf + t + u] = e[u];
      }
    }
    __syncthreads();
  }
}

extern "C" void kernel_launch(void* const* d_in, const int* in_sizes, int n_in,
                              void* d_out, int out_size, void* d_ws, size_t ws_size,
                              hipStream_t stream) {
  const float* x = (const float*)d_in[0];
  const float* w = (const float*)d_in[1];
  const float* b = (const float*)d_in[2];
  float* out = (float*)d_out;

  unsigned short* wsw = (unsigned short*)d_ws;   // 1 MB bf16 swizzled w

  conv1d_prep<<<(F_TOT * C_TOT * KW / 4 + 255) / 256, 256, 0, stream>>>(w, wsw);

  dim3 grid(32, N_BATCH);  // (16 t-blocks x 2 f-halves) x 32 = 1024 blocks
  conv1d_mfma<<<grid, 256, 0, stream>>>(x, wsw, b, out);
}

// Round 2
// 197.499 us; speedup vs baseline: 1.1420x; 1.1420x over previous
//
#include <hip/hip_runtime.h>

// Conv1d as implicit GEMM on MFMA bf16 — R7.
// out[n,f,t] = sum_{c,k} x[n,c,t+k] * w[f,c,k] + b[f]
// N=32, C=64, W=4096, F=128, WW=64, out_W=4033. Output fp32.
//
// R7 vs R5 (R6's F-split regressed: spills + lower per-wave duty; reverted):
//  * GEMM K-dim switched from filter-taps to CHANNELS. x is transpose-staged
//    ONCE per block as bf16 [t][c] (320 x 64, row stride 72 shorts = 144 B,
//    even bank spread). w streamed as [k][f][c] 16 KB slices, double-buffered
//    via linear global_load_lds.
//  * A-fragments are now plain aligned ds_read_b128 from the static x tile
//    (row offset +k per tap) — the alignbit sliding-window rebuild and its
//    lgkmcnt->VALU->MFMA critical path are GONE.
//  * B c-chunks XOR-swizzled by f&7 in prep (even bank spread on reads).
//  * Per wave per k: 64 MFMA vs 24 conflict-free ds_read_b128 + 4 async16;
//    regs ~190 (acc 128 + frags) -> compiler has pipelining room.

#define C_TOT   64
#define F_TOT   128
#define KW      64
#define OUT_W   4033
#define W_IN    4096
#define N_BATCH 32
#define T_BLK   256
#define XROWS   320
#define XSTR    72            // x tile row stride in shorts (144 B)
#define TRS     260           // transpose LDS row stride (dwords)
#define BK_SH   8192          // shorts per w k-slice (128 f x 64 c)

typedef __attribute__((ext_vector_type(8))) short  short8;
typedef __attribute__((ext_vector_type(4))) float  floatx4;

__device__ inline unsigned short f32_to_bf16(float f) {
  unsigned int u = __float_as_uint(f);
  u += 0x7FFF + ((u >> 16) & 1);
  return (unsigned short)(u >> 16);
}

__device__ inline void async16(const unsigned short* g, unsigned short* l) {
  __builtin_amdgcn_global_load_lds(
      (const __attribute__((address_space(1))) unsigned int*)g,
      (__attribute__((address_space(3))) unsigned int*)l, 16, 0, 0);
}

// ---- prep: w[f][c][k] fp32 -> wsw[k][f][(c>>3)^(f&7)][c&7] bf16 ----
__global__ __launch_bounds__(256) void conv1d_prep(
    const float* __restrict__ w, unsigned short* __restrict__ wsw) {
  int i4 = blockIdx.x * 256 + threadIdx.x;
  if (i4 < F_TOT * C_TOT * KW / 4) {
    int c4 = (i4 & 15) * 4;          // 0,4,...,60 (stays inside one 8-chunk)
    int f  = (i4 >> 4) & 127;
    int k  = i4 >> 11;
    const float* src = w + ((size_t)f * C_TOT + c4) * KW + k;
    ushort4 o;
    o.x = f32_to_bf16(src[0 * KW]);
    o.y = f32_to_bf16(src[1 * KW]);
    o.z = f32_to_bf16(src[2 * KW]);
    o.w = f32_to_bf16(src[3 * KW]);
    int chunk = (c4 >> 3) ^ (f & 7);
    *(ushort4*)&wsw[((size_t)(k * F_TOT + f) * 8 + chunk) * 8 + (c4 & 7)] = o;
  }
}

// ---------------- main GEMM ----------------
__global__ __launch_bounds__(256, 2) void conv1d_mfma(
    const float* __restrict__ x, const unsigned short* __restrict__ wsw,
    const float* __restrict__ b, float* __restrict__ out) {
  __shared__ union SM {
    unsigned short xt[XROWS * XSTR];   // 46.1 KB  x tile, bf16 [t][c]
    float tr[32 * TRS];                // 33.3 KB  epilogue transpose (overlay)
  } sm;
  __shared__ unsigned short bls[2][BK_SH];  // 2 x 16 KB w slices

  const int tid  = threadIdx.x;
  const int lane = tid & 63;
  const int wv   = tid >> 6;     // 0..3
  const int q    = lane >> 4;    // 0..3
  const int col  = lane & 15;
  const int n    = blockIdx.y;
  const int t0   = blockIdx.x * T_BLK;
  const int fh2  = wv & 1;       // f half (64 f)
  const int th   = wv >> 1;      // t half (128 t)

  const float* xrowb = x + (size_t)n * C_TOT * W_IN;

  floatx4 acc[8][4];             // [ms][ft]
#pragma unroll
  for (int ms = 0; ms < 8; ++ms)
#pragma unroll
    for (int ft = 0; ft < 4; ++ft) acc[ms][ft] = (floatx4)0.0f;

#define STAGE_B(k_, p_)                                                        \
  {                                                                            \
    const unsigned short* wb = wsw + (size_t)(k_) * BK_SH;                     \
    _Pragma("unroll")                                                          \
    for (int s = 0; s < 4; ++s) {                                              \
      int off = ((wv * 4 + s) * 64 + lane) * 8;                                \
      async16(wb + off, &bls[p_][off]);                                        \
    }                                                                          \
  }

  // prologue: start w slice k=0, then transpose-stage x tile
  STAGE_B(0, 0)
#pragma unroll 4
  for (int it = 0; it < 20; ++it) {
    int j  = it * 256 + tid;        // 0..5119 float4 jobs
    int c  = j / 80;                // 0..63
    int tq = j - c * 80;            // 0..79
    int gt = t0 + tq * 4;
    const float* src = xrowb + (size_t)c * W_IN + gt;
    float4 v = {0.f, 0.f, 0.f, 0.f};
    if (gt + 3 < W_IN) v = *(const float4*)src;
    else {
      if (gt < W_IN)     v.x = src[0];
      if (gt + 1 < W_IN) v.y = src[1];
      if (gt + 2 < W_IN) v.z = src[2];
    }
    int rb = tq * 4;
    sm.xt[(rb + 0) * XSTR + c] = f32_to_bf16(v.x);
    sm.xt[(rb + 1) * XSTR + c] = f32_to_bf16(v.y);
    sm.xt[(rb + 2) * XSTR + c] = f32_to_bf16(v.z);
    sm.xt[(rb + 3) * XSTR + c] = f32_to_bf16(v.w);
  }
  __syncthreads();

#pragma unroll 2
  for (int k = 0; k < KW; ++k) {
    const int p = k & 1;
    if (k + 1 < KW) STAGE_B(k + 1, p ^ 1)

    // A base: matrix row m = col, t = 128*th + 16*ms + m + k; c = cstep*32+q*8
    const unsigned short* xk = &sm.xt[(th * 128 + col + k) * XSTR + q * 8];
    const unsigned short* bp = &bls[p][(fh2 * 64 + col) * 64];

#pragma unroll
    for (int cstep = 0; cstep < 2; ++cstep) {
      short8 Bf[4];
#pragma unroll
      for (int ft = 0; ft < 4; ++ft)
        Bf[ft] = *(const short8*)&bp[ft * 1024 + (((cstep << 2) + q) ^ (col & 7)) * 8];
#pragma unroll
      for (int ms = 0; ms < 8; ++ms) {
        const short8 Af = *(const short8*)&xk[ms * 16 * XSTR + cstep * 32];
#pragma unroll
        for (int ft = 0; ft < 4; ++ft)
          acc[ms][ft] =
              __builtin_amdgcn_mfma_f32_16x16x32_bf16(Af, Bf[ft], acc[ms][ft], 0, 0, 0);
      }
    }
    __syncthreads();
  }

  // ---- epilogue: LDS transpose to [f][t], coalesced float4 stores ----
  // D layout: t_loc = 128*th + 16*ms + 4*q + r, f = 64*fh2 + 16*ft + col
  const int fs_w  = fh2 * 16 + col;     // f-slot for writes (0..31)
  const int fs_r  = tid >> 3;           // f-slot for reads (0..31)
  const int seg   = tid & 7;
  const int f_r   = (fs_r >> 4) * 64 + (fs_r & 15);
  const size_t ob = ((size_t)n * F_TOT) * OUT_W;

#pragma unroll
  for (int j = 0; j < 4; ++j) {         // round j handles ft == j (COMPILE-TIME)
#pragma unroll
    for (int ms = 0; ms < 8; ++ms) {
      float4 vv;
      vv.x = acc[ms][j][0];
      vv.y = acc[ms][j][1];
      vv.z = acc[ms][j][2];
      vv.w = acc[ms][j][3];
      int tl = 128 * th + 16 * ms + 4 * q;
      *(float4*)&sm.tr[fs_w * TRS + tl] = vv;
    }
    __syncthreads();
    const int f = f_r + 16 * j;
    const float bias = b[f];
    const size_t obf = ob + (size_t)f * OUT_W;
#pragma unroll
    for (int j2 = 0; j2 < 8; ++j2) {
      int tl = seg * 4 + 32 * j2;
      float4 vv = *(const float4*)&sm.tr[fs_r * TRS + tl];
      vv.x += bias; vv.y += bias; vv.z += bias; vv.w += bias;
      int t = t0 + tl;
      if (t + 3 < OUT_W) {
        *(float4*)&out[obf + t] = vv;
      } else {
        float e[4] = {vv.x, vv.y, vv.z, vv.w};
#pragma unroll
        for (int u = 0; u < 4; ++u)
          if (t + u < OUT_W) out[obf + t + u] = e[u];
      }
    }
    __syncthreads();
  }
}

extern "C" void kernel_launch(void* const* d_in, const int* in_sizes, int n_in,
                              void* d_out, int out_size, void* d_ws, size_t ws_size,
                              hipStream_t stream) {
  const float* x = (const float*)d_in[0];
  const float* w = (const float*)d_in[1];
  const float* b = (const float*)d_in[2];
  float* out = (float*)d_out;

  unsigned short* wsw = (unsigned short*)d_ws;   // 1 MB bf16 [k][f][c] swizzled w

  conv1d_prep<<<(F_TOT * C_TOT * KW / 4 + 255) / 256, 256, 0, stream>>>(w, wsw);

  dim3 grid((OUT_W + T_BLK - 1) / T_BLK, N_BATCH);  // 16 x 32 = 512 blocks
  conv1d_mfma<<<grid, 256, 0, stream>>>(x, wsw, b, out);
}

// Round 3
// 194.723 us; speedup vs baseline: 1.1583x; 1.0143x over previous
//
#include <hip/hip_runtime.h>

// Conv1d as implicit GEMM on MFMA bf16 — R8.
// out[n,f,t] = sum_{c,k} x[n,c,t+k] * w[f,c,k] + b[f]
// N=32, C=64, W=4096, F=128, WW=64, out_W=4033. Output fp32.
//
// R8 vs R7 (channel-K kept; LDS read traffic was at 93% of MFMA pipe):
//  * Tap-PAIR processing (k, k+16): A-fragment for (ms,k) == (ms-1,k+16),
//    so 9 A ds_reads serve 2 taps (was 16 per 2 taps). Register-reused.
//  * C split into two halves (two passes, acc persists): K=32 = one MFMA
//    per fragment; xt shrinks to 320x40 shorts (25.6 KB).
//  * All strides padded to 40 shorts (80 B): xt rows AND w rows. Start
//    banks 20*col mod 32 = 8 distinct -> 2-way (free) on every b128 read.
//    No XOR swizzles.
//  * x staged via c-strided dword loads -> ushort4 LDS writes (c-contig):
//    the 32-way scalar-b16 staging conflicts are gone.
//  * w prep packs [gi][tap][f][c] chunks (20 KB) matching async16 lane
//    order; double-buffered. LDS total 74.3 KB -> 2 blocks/CU.

#define C_TOT    64
#define F_TOT    128
#define KW       64
#define OUT_W    4033
#define W_IN     4096
#define N_BATCH  32
#define T_BLK    256
#define XROWS    320
#define XSTR     40            // xt row stride (shorts) = 80 B
#define WROW     40            // w row stride (shorts), c 0..31 valid
#define TRS      260           // epilogue transpose row stride (dwords)
#define CHUNK_SH 10240         // shorts per w chunk: 2 taps x 128 f x 40

typedef __attribute__((ext_vector_type(8))) short  short8;
typedef __attribute__((ext_vector_type(4))) float  floatx4;

__device__ inline unsigned short f32_to_bf16(float f) {
  unsigned int u = __float_as_uint(f);
  u += 0x7FFF + ((u >> 16) & 1);
  return (unsigned short)(u >> 16);
}

__device__ inline void async16(const unsigned short* g, unsigned short* l) {
  __builtin_amdgcn_global_load_lds(
      (const __attribute__((address_space(1))) unsigned int*)g,
      (__attribute__((address_space(3))) unsigned int*)l, 16, 0, 0);
}

// ---- prep: w[f][c][k] fp32 -> wpk[gi][tap][f][c(40-pad)] bf16 ----
// gi = hc*32 + ph*16 + kb ; taps k = kb + 32*ph + 16*tap ; c = hc*32 + 0..31
__global__ __launch_bounds__(256) void conv1d_prep(
    const float* __restrict__ w, unsigned short* __restrict__ wsw) {
  int j = blockIdx.x * 256 + threadIdx.x;     // 131072 jobs (ushort4 each)
  if (j < 64 * 2 * 128 * 8) {
    int c4  = (j & 7) * 4;
    int f   = (j >> 3) & 127;
    int tap = (j >> 10) & 1;
    int gi  = j >> 11;
    int k   = (gi & 15) + 32 * ((gi >> 4) & 1) + 16 * tap;
    int cg0 = (gi >> 5) * 32 + c4;
    const float* src = w + ((size_t)f * C_TOT + cg0) * KW + k;
    ushort4 o;
    o.x = f32_to_bf16(src[0 * KW]);
    o.y = f32_to_bf16(src[1 * KW]);
    o.z = f32_to_bf16(src[2 * KW]);
    o.w = f32_to_bf16(src[3 * KW]);
    *(ushort4*)&wsw[((size_t)(gi * 2 + tap) * 128 + f) * WROW + c4] = o;
  }
}

// ---------------- main GEMM ----------------
__global__ __launch_bounds__(256, 2) void conv1d_mfma(
    const float* __restrict__ x, const unsigned short* __restrict__ wsw,
    const float* __restrict__ b, float* __restrict__ out) {
  __shared__ union SM {
    unsigned short xt[XROWS * XSTR];   // 25.6 KB  x tile bf16 [t][c-half]
    float tr[32 * TRS];                // 33.3 KB  epilogue overlay
  } sm;
  __shared__ unsigned short bls[2][CHUNK_SH];  // 2 x 20 KB w pair-chunks

  const int tid  = threadIdx.x;
  const int lane = tid & 63;
  const int q    = lane >> 4;    // 0..3  (K-chunk / D sub-row)
  const int col  = lane & 15;    // matrix row (A: t, B: f)
  const int wv   = tid >> 6;     // 0..3
  const int n    = blockIdx.y;
  const int t0   = blockIdx.x * T_BLK;
  const int fh2  = wv & 1;       // f half (64 f)
  const int th   = wv >> 1;      // t half (128 t)

  const float* xrowb = x + (size_t)n * C_TOT * W_IN;

  floatx4 acc[8][4];             // [ms][ft]
#pragma unroll
  for (int ms = 0; ms < 8; ++ms)
#pragma unroll
    for (int ft = 0; ft < 4; ++ft) acc[ms][ft] = (floatx4)0.0f;

#define STAGE_W(gi_, p_)                                                       \
  {                                                                            \
    const unsigned short* wb = wsw + (size_t)(gi_) * CHUNK_SH;                 \
    _Pragma("unroll")                                                          \
    for (int s = 0; s < 5; ++s) {                                              \
      int off = (s * 256 + tid) * 8;                                           \
      async16(wb + off, &bls[p_][off]);                                        \
    }                                                                          \
  }

  // x stage for one c-half: c-strided dword loads -> ushort4 writes (c-contig)
#define STAGE_X(hc_)                                                           \
  {                                                                            \
    _Pragma("unroll")                                                          \
    for (int r = 0; r < 10; ++r) {                                             \
      int ti = (r % 5) * 64 + (tid & 63);                                      \
      int cl = ((r / 5) * 4 + (tid >> 6)) * 4;                                 \
      int gt = t0 + ti;                                                        \
      const float* src = xrowb + (size_t)((hc_) * 32 + cl) * W_IN + gt;        \
      float4 v = {0.f, 0.f, 0.f, 0.f};                                         \
      if (gt < W_IN) {                                                         \
        v.x = src[0];                                                          \
        v.y = src[W_IN];                                                       \
        v.z = src[2 * W_IN];                                                   \
        v.w = src[3 * W_IN];                                                   \
      }                                                                        \
      ushort4 o;                                                               \
      o.x = f32_to_bf16(v.x); o.y = f32_to_bf16(v.y);                          \
      o.z = f32_to_bf16(v.z); o.w = f32_to_bf16(v.w);                          \
      *(ushort4*)&sm.xt[ti * XSTR + cl] = o;                                   \
    }                                                                          \
  }

  // prologue
  STAGE_W(0, 0)
  STAGE_X(0)
  __syncthreads();

  for (int gi = 0; gi < 64; ++gi) {
    const int p = gi & 1;
    if (gi + 1 < 64) STAGE_W(gi + 1, p ^ 1)

    const int k1 = (gi & 15) + 32 * ((gi >> 4) & 1);   // taps (k1, k1+16)
    const unsigned short* ap = &sm.xt[(128 * th + col + k1) * XSTR + q * 8];
    const unsigned short* bp = &bls[p][(fh2 * 64 + col) * WROW + q * 8];

    // 9 A-fragments serve both taps: tap0 uses A[ms], tap1 uses A[ms+1]
    short8 A[9];
#pragma unroll
    for (int jj = 0; jj < 9; ++jj)
      A[jj] = *(const short8*)&ap[jj * 16 * XSTR];

#pragma unroll
    for (int tap = 0; tap < 2; ++tap) {
#pragma unroll
      for (int ft = 0; ft < 4; ++ft) {
        const short8 B = *(const short8*)&bp[(tap * 128 + ft * 16) * WROW];
#pragma unroll
        for (int ms = 0; ms < 8; ++ms)
          acc[ms][ft] = __builtin_amdgcn_mfma_f32_16x16x32_bf16(
              A[ms + tap], B, acc[ms][ft], 0, 0, 0);
      }
    }
    __syncthreads();
    if (gi == 31) {      // switch to c-half 1 (xt readers all done)
      STAGE_X(1)
      __syncthreads();
    }
  }

  // ---- epilogue: LDS transpose to [f][t], coalesced float4 stores ----
  // D layout: t_loc = 128*th + 16*ms + 4*q + r, f = 64*fh2 + 16*ft + col
  const int fs_w  = fh2 * 16 + col;     // f-slot for writes (0..31)
  const int fs_r  = tid >> 3;           // f-slot for reads (0..31)
  const int seg   = tid & 7;
  const int f_r   = (fs_r >> 4) * 64 + (fs_r & 15);
  const size_t ob = ((size_t)n * F_TOT) * OUT_W;

#pragma unroll
  for (int j = 0; j < 4; ++j) {         // round j handles ft == j (COMPILE-TIME)
#pragma unroll
    for (int ms = 0; ms < 8; ++ms) {
      float4 vv;
      vv.x = acc[ms][j][0];
      vv.y = acc[ms][j][1];
      vv.z = acc[ms][j][2];
      vv.w = acc[ms][j][3];
      int tl = 128 * th + 16 * ms + 4 * q;
      *(float4*)&sm.tr[fs_w * TRS + tl] = vv;
    }
    __syncthreads();
    const int f = f_r + 16 * j;
    const float bias = b[f];
    const size_t obf = ob + (size_t)f * OUT_W;
#pragma unroll
    for (int j2 = 0; j2 < 8; ++j2) {
      int tl = seg * 4 + 32 * j2;
      float4 vv = *(const float4*)&sm.tr[fs_r * TRS + tl];
      vv.x += bias; vv.y += bias; vv.z += bias; vv.w += bias;
      int t = t0 + tl;
      if (t + 3 < OUT_W) {
        *(float4*)&out[obf + t] = vv;
      } else {
        float e[4] = {vv.x, vv.y, vv.z, vv.w};
#pragma unroll
        for (int u = 0; u < 4; ++u)
          if (t + u < OUT_W) out[obf + t + u] = e[u];
      }
    }
    __syncthreads();
  }
}

extern "C" void kernel_launch(void* const* d_in, const int* in_sizes, int n_in,
                              void* d_out, int out_size, void* d_ws, size_t ws_size,
                              hipStream_t stream) {
  const float* x = (const float*)d_in[0];
  const float* w = (const float*)d_in[1];
  const float* b = (const float*)d_in[2];
  float* out = (float*)d_out;

  unsigned short* wsw = (unsigned short*)d_ws;   // 1.25 MB packed bf16 w

  conv1d_prep<<<512, 256, 0, stream>>>(w, wsw);

  dim3 grid((OUT_W + T_BLK - 1) / T_BLK, N_BATCH);  // 16 x 32 = 512 blocks
  conv1d_mfma<<<grid, 256, 0, stream>>>(x, wsw, b, out);
}

// Round 5
// 188.758 us; speedup vs baseline: 1.1949x; 1.0316x over previous
//
#include <hip/hip_runtime.h>

// Conv1d as implicit GEMM on MFMA bf16 — R9 (resubmit; R4 bench was an
// infra failure: GPU acquisition timeout, kernel never ran).
// out[n,f,t] = sum_{c,k} x[n,c,t+k] * w[f,c,k] + b[f]
// N=32, C=64, W=4096, F=128, WW=64, out_W=4033. Output fp32.
//
// R9 vs R8: barrier-free main loop; B operands global->register.
//  * R8 diagnosis: wall/iter = LDS + MFMA summed -> lockstep barriers
//    serialize the pipes. Cause of barriers: cooperative w staging in LDS.
//  * Fix: prep packs w into per-wave FRAGMENT layout (frag = 64 lanes x
//    16 B contiguous). Kernel loads B via one coalesced dwordx4 per frag
//    straight to registers (w = 1 MB, L2-resident). bls / async16 / all
//    main-loop barriers DELETED. Waves run free; HW overlaps one wave's
//    loads with another's MFMAs.
//  * B register double-buffer: tap1 loaded early in-iter, next-iter tap0
//    prefetched before MFMA cluster; static ping-pong (no runtime idx).
//  * setprio(1) around MFMA cluster (2 independent blocks/CU arbitrate).
//  * LDS now just xt (25.6 KB) U tr (33.3 KB) = 33.3 KB; 2 blocks/CU is
//    register-capped (acc 128 + A 36 + B 48 ~= 227 < 256 @ 2 waves/SIMD).

#define C_TOT    64
#define F_TOT    128
#define KW       64
#define OUT_W    4033
#define W_IN     4096
#define N_BATCH  32
#define T_BLK    256
#define XROWS    320
#define XSTR     40            // xt row stride (shorts) = 80 B
#define TRS      260           // epilogue transpose row stride (dwords)

typedef __attribute__((ext_vector_type(8))) short  short8;
typedef __attribute__((ext_vector_type(4))) float  floatx4;

__device__ inline unsigned short f32_to_bf16(float f) {
  unsigned int u = __float_as_uint(f);
  u += 0x7FFF + ((u >> 16) & 1);
  return (unsigned short)(u >> 16);
}

// ---- prep: w[f][c][k] fp32 -> frag-packed bf16 ----
// frag id = ((gi*2 + tap)*2 + fh2)*4 + ft ; lane = q*16 + col ; elem e 0..7
//   k = (gi&15) + 32*((gi>>4)&1) + 16*tap
//   f = fh2*64 + ft*16 + col
//   c = (gi>>5)*32 + q*8 + e
// short index = frag*512 + lane*8 + e   (total 1 MB, no padding)
__global__ __launch_bounds__(256) void conv1d_prep(
    const float* __restrict__ w, unsigned short* __restrict__ wsw) {
  int j = blockIdx.x * 256 + threadIdx.x;     // 131072 ushort4 jobs
  if (j < 131072) {
    int e4  = (j & 1) * 4;
    int col = (j >> 1) & 15;
    int q   = (j >> 5) & 3;
    int ft  = (j >> 7) & 3;
    int fh2 = (j >> 9) & 1;
    int tap = (j >> 10) & 1;
    int gi  = j >> 11;
    int k   = (gi & 15) + 32 * ((gi >> 4) & 1) + 16 * tap;
    int f   = fh2 * 64 + ft * 16 + col;
    int c0  = (gi >> 5) * 32 + q * 8 + e4;
    const float* src = w + ((size_t)f * C_TOT + c0) * KW + k;
    ushort4 o;
    o.x = f32_to_bf16(src[0 * KW]);
    o.y = f32_to_bf16(src[1 * KW]);
    o.z = f32_to_bf16(src[2 * KW]);
    o.w = f32_to_bf16(src[3 * KW]);
    *(ushort4*)&wsw[(size_t)j * 4] = o;
  }
}

// ---------------- main GEMM ----------------
__global__ __launch_bounds__(256, 2) void conv1d_mfma(
    const float* __restrict__ x, const unsigned short* __restrict__ wsw,
    const float* __restrict__ b, float* __restrict__ out) {
  __shared__ union SM {
    unsigned short xt[XROWS * XSTR];   // 25.6 KB  x tile bf16 [t][c-half]
    float tr[32 * TRS];                // 33.3 KB  epilogue overlay
  } sm;

  const int tid  = threadIdx.x;
  const int lane = tid & 63;
  const int q    = lane >> 4;    // 0..3
  const int col  = lane & 15;
  const int wv   = tid >> 6;     // 0..3
  const int n    = blockIdx.y;
  const int t0   = blockIdx.x * T_BLK;
  const int fh2  = wv & 1;       // f half (64 f)
  const int th   = wv >> 1;      // t half (128 t)

  const float* xrowb = x + (size_t)n * C_TOT * W_IN;
  const short8* wf = (const short8*)wsw;   // fragment granularity

  floatx4 acc[8][4];             // [ms][ft]
#pragma unroll
  for (int ms = 0; ms < 8; ++ms)
#pragma unroll
    for (int ft = 0; ft < 4; ++ft) acc[ms][ft] = (floatx4)0.0f;

  // x stage for one c-half: c-strided dword loads -> ushort4 writes
#define STAGE_X(hc_)                                                           \
  {                                                                            \
    _Pragma("unroll")                                                          \
    for (int r = 0; r < 10; ++r) {                                             \
      int ti = (r % 5) * 64 + (tid & 63);                                      \
      int cl = ((r / 5) * 4 + (tid >> 6)) * 4;                                 \
      int gt = t0 + ti;                                                        \
      const float* src = xrowb + (size_t)((hc_) * 32 + cl) * W_IN + gt;        \
      float4 v = {0.f, 0.f, 0.f, 0.f};                                         \
      if (gt < W_IN) {                                                         \
        v.x = src[0];                                                          \
        v.y = src[W_IN];                                                       \
        v.z = src[2 * W_IN];                                                   \
        v.w = src[3 * W_IN];                                                   \
      }                                                                        \
      ushort4 o;                                                               \
      o.x = f32_to_bf16(v.x); o.y = f32_to_bf16(v.y);                          \
      o.z = f32_to_bf16(v.z); o.w = f32_to_bf16(v.w);                          \
      *(ushort4*)&sm.xt[ti * XSTR + cl] = o;                                   \
    }                                                                          \
  }

  // frag index: ((gi*2 + tap)*2 + fh2)*256 + ft*64 + lane  (short8 units)
#define BFRAG(gi_, tap_, ft_) \
  wf[(size_t)(((gi_) * 2 + (tap_)) * 2 + fh2) * 256 + (ft_) * 64 + lane]

  // One iteration: taps (k1, k1+16) of c-half gi>>5.
  // Bt0_ holds tap0 frags (prefetched last iter); Bn_ receives next tap0.
#define BODY(gi_, Bt0_, Bn_)                                                   \
  {                                                                            \
    const int k1 = ((gi_) & 15) + 32 * (((gi_) >> 4) & 1);                     \
    short8 Bt1[4];                                                             \
    _Pragma("unroll")                                                          \
    for (int ft = 0; ft < 4; ++ft) Bt1[ft] = BFRAG(gi_, 1, ft);                \
    const unsigned short* ap = &sm.xt[(128 * th + col + k1) * XSTR + q * 8];   \
    short8 A[9];                                                               \
    _Pragma("unroll")                                                          \
    for (int jj = 0; jj < 9; ++jj)                                             \
      A[jj] = *(const short8*)&ap[jj * 16 * XSTR];                             \
    if ((gi_) + 1 < 64) {                                                      \
      _Pragma("unroll")                                                        \
      for (int ft = 0; ft < 4; ++ft) Bn_[ft] = BFRAG((gi_) + 1, 0, ft);        \
    }                                                                          \
    __builtin_amdgcn_s_setprio(1);                                             \
    _Pragma("unroll")                                                          \
    for (int ft = 0; ft < 4; ++ft)                                             \
      _Pragma("unroll")                                                        \
      for (int ms = 0; ms < 8; ++ms)                                           \
        acc[ms][ft] = __builtin_amdgcn_mfma_f32_16x16x32_bf16(                 \
            A[ms], Bt0_[ft], acc[ms][ft], 0, 0, 0);                            \
    _Pragma("unroll")                                                          \
    for (int ft = 0; ft < 4; ++ft)                                             \
      _Pragma("unroll")                                                        \
      for (int ms = 0; ms < 8; ++ms)                                           \
        acc[ms][ft] = __builtin_amdgcn_mfma_f32_16x16x32_bf16(                 \
            A[ms + 1], Bt1[ft], acc[ms][ft], 0, 0, 0);                         \
    __builtin_amdgcn_s_setprio(0);                                             \
  }

  // prologue: stage x c-half 0, preload gi=0 tap0 frags
  STAGE_X(0)
  short8 B0[4], B1[4];
#pragma unroll
  for (int ft = 0; ft < 4; ++ft) B0[ft] = BFRAG(0, 0, ft);
  __syncthreads();

  for (int g2 = 0; g2 < 32; ++g2) {
    const int gi = 2 * g2;
    BODY(gi, B0, B1)
    BODY(gi + 1, B1, B0)
    if (gi + 1 == 31) {          // c-half switch (xt readers all done)
      __syncthreads();
      STAGE_X(1)
      __syncthreads();
    }
  }
  __syncthreads();               // waves may drift: resync before tr overlay

  // ---- epilogue: LDS transpose to [f][t], coalesced float4 stores ----
  // D layout: t_loc = 128*th + 16*ms + 4*q + r, f = 64*fh2 + 16*ft + col
  const int fs_w  = fh2 * 16 + col;     // f-slot for writes (0..31)
  const int fs_r  = tid >> 3;           // f-slot for reads (0..31)
  const int seg   = tid & 7;
  const int f_r   = (fs_r >> 4) * 64 + (fs_r & 15);
  const size_t ob = ((size_t)n * F_TOT) * OUT_W;

#pragma unroll
  for (int j = 0; j < 4; ++j) {         // round j handles ft == j (COMPILE-TIME)
#pragma unroll
    for (int ms = 0; ms < 8; ++ms) {
      float4 vv;
      vv.x = acc[ms][j][0];
      vv.y = acc[ms][j][1];
      vv.z = acc[ms][j][2];
      vv.w = acc[ms][j][3];
      int tl = 128 * th + 16 * ms + 4 * q;
      *(float4*)&sm.tr[fs_w * TRS + tl] = vv;
    }
    __syncthreads();
    const int f = f_r + 16 * j;
    const float bias = b[f];
    const size_t obf = ob + (size_t)f * OUT_W;
#pragma unroll
    for (int j2 = 0; j2 < 8; ++j2) {
      int tl = seg * 4 + 32 * j2;
      float4 vv = *(const float4*)&sm.tr[fs_r * TRS + tl];
      vv.x += bias; vv.y += bias; vv.z += bias; vv.w += bias;
      int t = t0 + tl;
      if (t + 3 < OUT_W) {
        *(float4*)&out[obf + t] = vv;
      } else {
        float e[4] = {vv.x, vv.y, vv.z, vv.w};
#pragma unroll
        for (int u = 0; u < 4; ++u)
          if (t + u < OUT_W) out[obf + t + u] = e[u];
      }
    }
    __syncthreads();
  }
}

extern "C" void kernel_launch(void* const* d_in, const int* in_sizes, int n_in,
                              void* d_out, int out_size, void* d_ws, size_t ws_size,
                              hipStream_t stream) {
  const float* x = (const float*)d_in[0];
  const float* w = (const float*)d_in[1];
  const float* b = (const float*)d_in[2];
  float* out = (float*)d_out;

  unsigned short* wsw = (unsigned short*)d_ws;   // 1 MB frag-packed bf16 w

  conv1d_prep<<<512, 256, 0, stream>>>(w, wsw);

  dim3 grid((OUT_W + T_BLK - 1) / T_BLK, N_BATCH);  // 16 x 32 = 512 blocks
  conv1d_mfma<<<grid, 256, 0, stream>>>(x, wsw, b, out);
}